// Round 1
// baseline (299.400 us; speedup 1.0000x reference)
//
#include <hip/hip_runtime.h>
#include <math.h>

constexpr int B = 4;
constexpr int N = 16384;
constexpr int D = 256;
constexpr int M = 64;
constexpr int H = 8;
// HD = 32, 3D = 768

__device__ __forceinline__ float4 ld4(const float* p) {
  return *reinterpret_cast<const float4*>(p);
}
__device__ __forceinline__ void st4(float* p, float a, float b, float c, float d) {
  *reinterpret_cast<float4*>(p) = make_float4(a, b, c, d);
}

#define FMA16(acc, a4, b4)                       \
  do {                                           \
    acc[0][0] = fmaf(a4.x, b4.x, acc[0][0]);     \
    acc[0][1] = fmaf(a4.x, b4.y, acc[0][1]);     \
    acc[0][2] = fmaf(a4.x, b4.z, acc[0][2]);     \
    acc[0][3] = fmaf(a4.x, b4.w, acc[0][3]);     \
    acc[1][0] = fmaf(a4.y, b4.x, acc[1][0]);     \
    acc[1][1] = fmaf(a4.y, b4.y, acc[1][1]);     \
    acc[1][2] = fmaf(a4.y, b4.z, acc[1][2]);     \
    acc[1][3] = fmaf(a4.y, b4.w, acc[1][3]);     \
    acc[2][0] = fmaf(a4.z, b4.x, acc[2][0]);     \
    acc[2][1] = fmaf(a4.z, b4.y, acc[2][1]);     \
    acc[2][2] = fmaf(a4.z, b4.z, acc[2][2]);     \
    acc[2][3] = fmaf(a4.z, b4.w, acc[2][3]);     \
    acc[3][0] = fmaf(a4.w, b4.x, acc[3][0]);     \
    acc[3][1] = fmaf(a4.w, b4.y, acc[3][1]);     \
    acc[3][2] = fmaf(a4.w, b4.z, acc[3][2]);     \
    acc[3][3] = fmaf(a4.w, b4.w, acc[3][3]);     \
  } while (0)

// K1: E[b,n,m] = exp(x[b,n,:] . Ws[m,:] + bs[m]); denom[b,m] += sum_n E
// grid (N/64, B), block 256
__global__ __launch_bounds__(256) void k1_logits_exp(
    const float* __restrict__ x, const float* __restrict__ Ws,
    const float* __restrict__ bs, float* __restrict__ E,
    float* __restrict__ denom) {
  __shared__ float At[32][68];  // x^T chunk [k][n]
  __shared__ float Bt[32][68];  // Ws^T chunk [k][m]
  const int b = blockIdx.y;
  const int n0 = blockIdx.x * 64;
  const int tid = threadIdx.x;
  const int tm4 = (tid & 15) * 4;  // m
  const int tn4 = (tid >> 4) * 4;  // n

  float acc[4][4] = {};
  for (int kc = 0; kc < 8; ++kc) {
    __syncthreads();
    for (int i = tid; i < 512; i += 256) {
      const int r = i >> 3;
      const int kq = (i & 7) * 4;
      float4 xa = ld4(&x[((size_t)(b * N + n0 + r)) * D + kc * 32 + kq]);
      At[kq + 0][r] = xa.x; At[kq + 1][r] = xa.y;
      At[kq + 2][r] = xa.z; At[kq + 3][r] = xa.w;
      float4 wb = ld4(&Ws[(size_t)r * D + kc * 32 + kq]);
      Bt[kq + 0][r] = wb.x; Bt[kq + 1][r] = wb.y;
      Bt[kq + 2][r] = wb.z; Bt[kq + 3][r] = wb.w;
    }
    __syncthreads();
    for (int k = 0; k < 32; ++k) {
      float4 a4 = ld4(&At[k][tn4]);
      float4 b4 = ld4(&Bt[k][tm4]);
      FMA16(acc, a4, b4);
    }
  }
  float4 bsv = ld4(&bs[tm4]);
  const float bsa[4] = {bsv.x, bsv.y, bsv.z, bsv.w};
  float cs[4] = {0.f, 0.f, 0.f, 0.f};
#pragma unroll
  for (int i = 0; i < 4; ++i) {
    float e0 = expf(acc[i][0] + bsa[0]);
    float e1 = expf(acc[i][1] + bsa[1]);
    float e2 = expf(acc[i][2] + bsa[2]);
    float e3 = expf(acc[i][3] + bsa[3]);
    st4(&E[((size_t)(b * N + n0 + tn4 + i)) * M + tm4], e0, e1, e2, e3);
    cs[0] += e0; cs[1] += e1; cs[2] += e2; cs[3] += e3;
  }
  __syncthreads();
  float* red = &At[0][0];
  if (tid < 64) red[tid] = 0.0f;
  __syncthreads();
  atomicAdd(&red[tm4 + 0], cs[0]);
  atomicAdd(&red[tm4 + 1], cs[1]);
  atomicAdd(&red[tm4 + 2], cs[2]);
  atomicAdd(&red[tm4 + 3], cs[3]);
  __syncthreads();
  if (tid < 64) atomicAdd(&denom[b * M + tid], red[tid]);
}

// K2: tokens_raw[b,m,d] += sum_n E[b,n,m] * x[b,n,d]  (split-K over N)
// grid (D/64, N/512, B), block 256
__global__ __launch_bounds__(256) void k2_pool(
    const float* __restrict__ x, const float* __restrict__ E,
    float* __restrict__ tokens) {
  __shared__ float Am[32][68];  // E chunk [n][m]
  __shared__ float Bd[32][68];  // x chunk [n][d]
  const int dt = blockIdx.x;
  const int nc = blockIdx.y;
  const int b = blockIdx.z;
  const int tid = threadIdx.x;
  const int tm4 = (tid & 15) * 4;  // d
  const int tn4 = (tid >> 4) * 4;  // m
  float acc[4][4] = {};
  for (int kc = 0; kc < 16; ++kc) {
    const int nb = nc * 512 + kc * 32;
    __syncthreads();
    for (int i = tid; i < 512; i += 256) {
      const int n = i >> 4;
      const int c4 = (i & 15) * 4;
      *reinterpret_cast<float4*>(&Am[n][c4]) =
          ld4(&E[((size_t)(b * N + nb + n)) * M + c4]);
      *reinterpret_cast<float4*>(&Bd[n][c4]) =
          ld4(&x[((size_t)(b * N + nb + n)) * D + dt * 64 + c4]);
    }
    __syncthreads();
    for (int k = 0; k < 32; ++k) {
      float4 a4 = ld4(&Am[k][tn4]);
      float4 b4 = ld4(&Bd[k][tm4]);
      FMA16(acc, a4, b4);
    }
  }
#pragma unroll
  for (int i = 0; i < 4; ++i)
#pragma unroll
    for (int j = 0; j < 4; ++j)
      atomicAdd(&tokens[((size_t)(b * M + tn4 + i)) * D + dt * 64 + tm4 + j],
                acc[i][j]);
}

// K3/K5: Out[b,m,e] = (A[b,m,:] . W[e,:] + bias[e]) / denom[b,m]
// grid (EC/64, B), block 256
__global__ __launch_bounds__(256) void k_proj(
    const float* __restrict__ A, const float* __restrict__ W,
    const float* __restrict__ bias, const float* __restrict__ denom,
    float* __restrict__ Out, const int EC) {
  __shared__ float At[32][68];  // A^T chunk [k][m]
  __shared__ float Bt[32][68];  // W^T chunk [k][e]
  const int et = blockIdx.x;
  const int b = blockIdx.y;
  const int tid = threadIdx.x;
  const int tm4 = (tid & 15) * 4;  // e
  const int tn4 = (tid >> 4) * 4;  // m
  float acc[4][4] = {};
  for (int kc = 0; kc < 8; ++kc) {
    __syncthreads();
    for (int i = tid; i < 512; i += 256) {
      const int r = i >> 3;
      const int kq = (i & 7) * 4;
      float4 av = ld4(&A[((size_t)(b * M + r)) * D + kc * 32 + kq]);
      At[kq + 0][r] = av.x; At[kq + 1][r] = av.y;
      At[kq + 2][r] = av.z; At[kq + 3][r] = av.w;
      float4 wv = ld4(&W[((size_t)(et * 64 + r)) * D + kc * 32 + kq]);
      Bt[kq + 0][r] = wv.x; Bt[kq + 1][r] = wv.y;
      Bt[kq + 2][r] = wv.z; Bt[kq + 3][r] = wv.w;
    }
    __syncthreads();
    for (int k = 0; k < 32; ++k) {
      float4 a4 = ld4(&At[k][tn4]);
      float4 b4 = ld4(&Bt[k][tm4]);
      FMA16(acc, a4, b4);
    }
  }
  float bsv[4] = {0.f, 0.f, 0.f, 0.f};
  if (bias != nullptr) {
    float4 t = ld4(&bias[et * 64 + tm4]);
    bsv[0] = t.x; bsv[1] = t.y; bsv[2] = t.z; bsv[3] = t.w;
  }
#pragma unroll
  for (int i = 0; i < 4; ++i) {
    const float rcp = 1.0f / denom[b * M + tn4 + i];
    st4(&Out[((size_t)(b * M + tn4 + i)) * EC + et * 64 + tm4],
        (acc[i][0] + bsv[0]) * rcp, (acc[i][1] + bsv[1]) * rcp,
        (acc[i][2] + bsv[2]) * rcp, (acc[i][3] + bsv[3]) * rcp);
  }
}

// K4: per (b,h) attention over M=64 tokens, HD=32
// grid (B*H), block 256
__global__ __launch_bounds__(256) void k4_attn(
    const float* __restrict__ qkv, float* __restrict__ attn_o) {
  __shared__ float qt[32][68];  // q^T [hd][m]
  __shared__ float kt[32][68];  // k^T [hd][m]
  __shared__ float vv[64][36];  // v   [m][hd]
  __shared__ float P[64][68];   // scores / probs
  const int b = blockIdx.x >> 3;
  const int h = blockIdx.x & 7;
  const int tid = threadIdx.x;
  for (int i = tid; i < 512; i += 256) {
    const int m = i >> 3;
    const int c4 = (i & 7) * 4;
    const float* base = &qkv[((size_t)(b * M + m)) * 768 + h * 32 + c4];
    float4 q4 = ld4(base);
    float4 k4 = ld4(base + 256);
    float4 v4 = ld4(base + 512);
    qt[c4 + 0][m] = q4.x; qt[c4 + 1][m] = q4.y; qt[c4 + 2][m] = q4.z; qt[c4 + 3][m] = q4.w;
    kt[c4 + 0][m] = k4.x; kt[c4 + 1][m] = k4.y; kt[c4 + 2][m] = k4.z; kt[c4 + 3][m] = k4.w;
    *reinterpret_cast<float4*>(&vv[m][c4]) = v4;
  }
  __syncthreads();
  {
    const int tm4 = (tid & 15) * 4;  // j
    const int tn4 = (tid >> 4) * 4;  // i
    float acc[4][4] = {};
    for (int k = 0; k < 32; ++k) {
      float4 a4 = ld4(&qt[k][tn4]);
      float4 b4 = ld4(&kt[k][tm4]);
      FMA16(acc, a4, b4);
    }
    const float scale = 0.17677669529663687f;  // 1/sqrt(32)
#pragma unroll
    for (int i = 0; i < 4; ++i)
      st4(&P[tn4 + i][tm4], acc[i][0] * scale, acc[i][1] * scale,
          acc[i][2] * scale, acc[i][3] * scale);
  }
  __syncthreads();
  if (tid < 64) {
    float mx = -1e30f;
    for (int j = 0; j < 64; ++j) mx = fmaxf(mx, P[tid][j]);
    float s = 0.0f;
    for (int j = 0; j < 64; ++j) {
      const float e = expf(P[tid][j] - mx);
      P[tid][j] = e;
      s += e;
    }
    const float r = 1.0f / s;
    for (int j = 0; j < 64; ++j) P[tid][j] *= r;
  }
  __syncthreads();
  if (tid < 128) {
    const int i0 = (tid >> 3) * 4;
    const int c0 = (tid & 7) * 4;
    float o[4][4] = {};
    for (int j = 0; j < 64; ++j) {
      float4 v4 = ld4(&vv[j][c0]);
#pragma unroll
      for (int ii = 0; ii < 4; ++ii) {
        const float p = P[i0 + ii][j];
        o[ii][0] = fmaf(p, v4.x, o[ii][0]);
        o[ii][1] = fmaf(p, v4.y, o[ii][1]);
        o[ii][2] = fmaf(p, v4.z, o[ii][2]);
        o[ii][3] = fmaf(p, v4.w, o[ii][3]);
      }
    }
#pragma unroll
    for (int ii = 0; ii < 4; ++ii)
      st4(&attn_o[((size_t)(b * M + i0 + ii)) * D + h * 32 + c0],
          o[ii][0], o[ii][1], o[ii][2], o[ii][3]);
  }
}

// K6: out[b,n,d] = sum_m E[b,n,m] * Tp[b,m,d]   (Tp already has 1/denom folded)
// grid (D/64, N/64, B), block 256
__global__ __launch_bounds__(256) void k6_unpool(
    const float* __restrict__ E, const float* __restrict__ Tp,
    float* __restrict__ out) {
  __shared__ float Et[64][68];  // E^T tile [m][n]
  __shared__ float Tt[64][68];  // Tp tile [m][d]
  const int dt = blockIdx.x;
  const int nt = blockIdx.y;
  const int b = blockIdx.z;
  const int n0 = nt * 64;
  const int tid = threadIdx.x;
  const int tm4 = (tid & 15) * 4;  // d
  const int tn4 = (tid >> 4) * 4;  // n
  for (int i = tid; i < 1024; i += 256) {
    const int r = i >> 4;
    const int c4 = (i & 15) * 4;
    float4 ev = ld4(&E[((size_t)(b * N + n0 + r)) * M + c4]);
    Et[c4 + 0][r] = ev.x; Et[c4 + 1][r] = ev.y;
    Et[c4 + 2][r] = ev.z; Et[c4 + 3][r] = ev.w;
    *reinterpret_cast<float4*>(&Tt[r][c4]) =
        ld4(&Tp[((size_t)(b * M + r)) * D + dt * 64 + c4]);
  }
  __syncthreads();
  float acc[4][4] = {};
  for (int k = 0; k < 64; ++k) {
    float4 a4 = ld4(&Et[k][tn4]);
    float4 b4 = ld4(&Tt[k][tm4]);
    FMA16(acc, a4, b4);
  }
#pragma unroll
  for (int i = 0; i < 4; ++i)
    st4(&out[((size_t)(b * N + n0 + tn4 + i)) * D + dt * 64 + tm4],
        acc[i][0], acc[i][1], acc[i][2], acc[i][3]);
}

extern "C" void kernel_launch(void* const* d_in, const int* in_sizes, int n_in,
                              void* d_out, int out_size, void* d_ws,
                              size_t ws_size, hipStream_t stream) {
  const float* x = (const float*)d_in[0];
  const float* Ws = (const float*)d_in[1];
  const float* bs = (const float*)d_in[2];
  const float* Wqkv = (const float*)d_in[3];
  const float* Wo = (const float*)d_in[4];
  const float* bo = (const float*)d_in[5];
  float* out = (float*)d_out;

  float* ws = (float*)d_ws;
  float* E = ws;                                // B*N*M   = 4,194,304 f
  float* denom = E + (size_t)B * N * M;         // B*M     = 256 f
  float* tokens = denom + B * M;                // B*M*D   = 65,536 f
  float* qkv = tokens + (size_t)B * M * D;      // B*M*3D  = 196,608 f
  float* attn_o = qkv + (size_t)B * M * 3 * D;  // B*M*D   = 65,536 f
  float* Tp = attn_o + (size_t)B * M * D;       // B*M*D   = 65,536 f
  // total ws use: ~18.4 MB

  hipMemsetAsync(denom, 0, (size_t)B * M * sizeof(float), stream);
  hipMemsetAsync(tokens, 0, (size_t)B * M * D * sizeof(float), stream);

  k1_logits_exp<<<dim3(N / 64, B), 256, 0, stream>>>(x, Ws, bs, E, denom);
  k2_pool<<<dim3(D / 64, N / 512, B), 256, 0, stream>>>(x, E, tokens);
  k_proj<<<dim3(12, B), 256, 0, stream>>>(tokens, Wqkv, nullptr, denom, qkv, 768);
  k4_attn<<<dim3(B * H), 256, 0, stream>>>(qkv, attn_o);
  k_proj<<<dim3(4, B), 256, 0, stream>>>(attn_o, Wo, bo, denom, Tp, 256);
  k6_unpool<<<dim3(D / 64, N / 64, B), 256, 0, stream>>>(E, Tp, out);
}

// Round 2
// 230.614 us; speedup vs baseline: 1.2983x; 1.2983x over previous
//
#include <hip/hip_runtime.h>
#include <math.h>

constexpr int B = 4;
constexpr int N = 16384;
constexpr int D = 256;
constexpr int M = 64;
constexpr int H = 8;
// HD = 32, 3D = 768

typedef __attribute__((ext_vector_type(8))) short short8;
typedef __attribute__((ext_vector_type(4))) float floatx4;

__device__ __forceinline__ float4 ld4(const float* p) {
  return *reinterpret_cast<const float4*>(p);
}
__device__ __forceinline__ void st4(float* p, float a, float b, float c, float d) {
  *reinterpret_cast<float4*>(p) = make_float4(a, b, c, d);
}
__device__ __forceinline__ unsigned short f2bf(float f) {
  unsigned u = __float_as_uint(f);
  unsigned r = (u + 0x7fffu + ((u >> 16) & 1u)) >> 16;  // RNE
  return (unsigned short)r;
}
__device__ __forceinline__ float bf2f(unsigned short s) {
  return __uint_as_float(((unsigned)s) << 16);
}

#define FMA16(acc, a4, b4)                       \
  do {                                           \
    acc[0][0] = fmaf(a4.x, b4.x, acc[0][0]);     \
    acc[0][1] = fmaf(a4.x, b4.y, acc[0][1]);     \
    acc[0][2] = fmaf(a4.x, b4.z, acc[0][2]);     \
    acc[0][3] = fmaf(a4.x, b4.w, acc[0][3]);     \
    acc[1][0] = fmaf(a4.y, b4.x, acc[1][0]);     \
    acc[1][1] = fmaf(a4.y, b4.y, acc[1][1]);     \
    acc[1][2] = fmaf(a4.y, b4.z, acc[1][2]);     \
    acc[1][3] = fmaf(a4.y, b4.w, acc[1][3]);     \
    acc[2][0] = fmaf(a4.z, b4.x, acc[2][0]);     \
    acc[2][1] = fmaf(a4.z, b4.y, acc[2][1]);     \
    acc[2][2] = fmaf(a4.z, b4.z, acc[2][2]);     \
    acc[2][3] = fmaf(a4.z, b4.w, acc[2][3]);     \
    acc[3][0] = fmaf(a4.w, b4.x, acc[3][0]);     \
    acc[3][1] = fmaf(a4.w, b4.y, acc[3][1]);     \
    acc[3][2] = fmaf(a4.w, b4.z, acc[3][2]);     \
    acc[3][3] = fmaf(a4.w, b4.w, acc[3][3]);     \
  } while (0)

// ---------------------------------------------------------------------------
// K0: convert x -> xb (bf16, [b,n,d]) and xbT (bf16, [b,d,n]); convert Ws->Wsb
// grid (N/64, D/64, B), block 256
__global__ __launch_bounds__(256) void k0_cvt(
    const float* __restrict__ x, const float* __restrict__ Ws,
    unsigned short* __restrict__ xb, unsigned short* __restrict__ xbT,
    unsigned short* __restrict__ Wsb) {
  __shared__ float Xf[64][68];  // column-swizzled fp32 tile
  const int nt = blockIdx.x, dt = blockIdx.y, b = blockIdx.z;
  const int n0 = nt * 64, d0 = dt * 64;
  const int tid = threadIdx.x;
#pragma unroll
  for (int p = 0; p < 4; ++p) {
    const int i = p * 256 + tid;
    const int row = i >> 4;          // n-local
    const int c4 = (i & 15) * 4;     // d-local
    float4 v = ld4(&x[((size_t)(b * N + n0 + row)) * D + d0 + c4]);
    // xb store (straight convert)
    unsigned u0 = (unsigned)f2bf(v.x) | ((unsigned)f2bf(v.y) << 16);
    unsigned u1 = (unsigned)f2bf(v.z) | ((unsigned)f2bf(v.w) << 16);
    *reinterpret_cast<uint2*>(&xb[((size_t)(b * N + n0 + row)) * D + d0 + c4]) =
        make_uint2(u0, u1);
    // LDS with column swizzle: shift by 4*((row>>1)&15)
    const int cp = (c4 + 4 * ((row >> 1) & 15)) & 63;
    *reinterpret_cast<float4*>(&Xf[row][cp]) = v;
  }
  __syncthreads();
  // xbT: 64 d rows x 32 n-pairs = 2048 dwords
#pragma unroll
  for (int p = 0; p < 8; ++p) {
    const int gi = p * 256 + tid;
    const int np = gi & 31;
    const int dr = gi >> 5;  // 0..63
    const int s = 4 * (np & 15);
    const int cc = (((dr & ~3) + s) & 63) + (dr & 3);
    const float f0 = Xf[2 * np][cc];
    const float f1 = Xf[2 * np + 1][cc];
    const unsigned w = (unsigned)f2bf(f0) | ((unsigned)f2bf(f1) << 16);
    *reinterpret_cast<unsigned*>(
        &xbT[((size_t)(b * D + d0 + dr)) * N + n0 + 2 * np]) = w;
  }
  // Ws conversion (tiny): blocks with nt==0 && b==0
  if (nt == 0 && b == 0) {
#pragma unroll
    for (int p = 0; p < 4; ++p) {
      const int i = p * 256 + tid;
      const int row = i >> 4;
      const int c4 = (i & 15) * 4;
      float4 v = ld4(&Ws[(size_t)row * D + d0 + c4]);
      unsigned u0 = (unsigned)f2bf(v.x) | ((unsigned)f2bf(v.y) << 16);
      unsigned u1 = (unsigned)f2bf(v.z) | ((unsigned)f2bf(v.w) << 16);
      *reinterpret_cast<uint2*>(&Wsb[(size_t)row * D + d0 + c4]) =
          make_uint2(u0, u1);
    }
  }
}

// ---------------------------------------------------------------------------
// K1: logits = xb . Wsb^T; E = exp(logits + bs); write En[b,n,m], Et[b,m,n];
//     denom[b,m] += sum_n E.   MFMA 16x16x32 bf16.
// grid (N/64, B), block 256 (4 waves)
__global__ __launch_bounds__(256) void k1_logits(
    const unsigned short* __restrict__ xb, const unsigned short* __restrict__ Wsb,
    const float* __restrict__ bs, unsigned short* __restrict__ En,
    unsigned short* __restrict__ Et, float* __restrict__ denom) {
  __shared__ unsigned short Xt[64][264];  // x tile [n][k], padded
  __shared__ unsigned short Wt[64][264];  // Ws tile [m][k]
  __shared__ unsigned short Es[64][72];   // E tile [n][m] bf16
  __shared__ float red[64];
  const int b = blockIdx.y;
  const int n0 = blockIdx.x * 64;
  const int tid = threadIdx.x;
  const int w = tid >> 6, l = tid & 63;

#pragma unroll
  for (int p = 0; p < 8; ++p) {
    const int g = p * 256 + tid;
    const int row = g >> 5;
    const int c8 = (g & 31) * 8;
    *reinterpret_cast<short8*>(&Xt[row][c8]) =
        *reinterpret_cast<const short8*>(
            &xb[((size_t)(b * N + n0 + row)) * D + c8]);
    *reinterpret_cast<short8*>(&Wt[row][c8]) =
        *reinterpret_cast<const short8*>(&Wsb[(size_t)row * D + c8]);
  }
  if (tid < 64) red[tid] = 0.0f;
  __syncthreads();

  floatx4 acc[4] = {{0.f, 0.f, 0.f, 0.f},
                    {0.f, 0.f, 0.f, 0.f},
                    {0.f, 0.f, 0.f, 0.f},
                    {0.f, 0.f, 0.f, 0.f}};
  const int ar = w * 16 + (l & 15);
  const int q8 = (l >> 4) * 8;
#pragma unroll
  for (int ks = 0; ks < 8; ++ks) {
    short8 a = *reinterpret_cast<short8*>(&Xt[ar][ks * 32 + q8]);
#pragma unroll
    for (int mt = 0; mt < 4; ++mt) {
      short8 bf = *reinterpret_cast<short8*>(&Wt[mt * 16 + (l & 15)][ks * 32 + q8]);
      acc[mt] = __builtin_amdgcn_mfma_f32_16x16x32_bf16(a, bf, acc[mt], 0, 0, 0);
    }
  }
  // epilogue: exp + Es + denom partials
#pragma unroll
  for (int mt = 0; mt < 4; ++mt) {
    const int m = mt * 16 + (l & 15);
    const float bsm = bs[m];
    float s = 0.0f;
#pragma unroll
    for (int r = 0; r < 4; ++r) {
      const int n = w * 16 + (l >> 4) * 4 + r;
      const float e = expf(acc[mt][r] + bsm);
      s += e;
      Es[n][m] = f2bf(e);
    }
    atomicAdd(&red[m], s);
  }
  __syncthreads();
  if (tid < 64) atomicAdd(&denom[b * M + tid], red[tid]);
  // En writes (row-major, coalesced b128)
#pragma unroll
  for (int p = 0; p < 2; ++p) {
    const int g = p * 256 + tid;
    const int n = g >> 3;
    const int m0 = (g & 7) * 8;
    short8 v = *reinterpret_cast<short8*>(&Es[n][m0]);
    *reinterpret_cast<short8*>(&En[((size_t)(b * N + n0 + n)) * M + m0]) = v;
  }
  // Et writes (transposed)
#pragma unroll
  for (int p = 0; p < 2; ++p) {
    const int g = p * 256 + tid;
    const int m = g >> 3;
    const int n8 = (g & 7) * 8;
    unsigned short bu[8];
#pragma unroll
    for (int k = 0; k < 8; ++k) bu[k] = Es[n8 + k][m];
    uint4 pk;
    pk.x = (unsigned)bu[0] | ((unsigned)bu[1] << 16);
    pk.y = (unsigned)bu[2] | ((unsigned)bu[3] << 16);
    pk.z = (unsigned)bu[4] | ((unsigned)bu[5] << 16);
    pk.w = (unsigned)bu[6] | ((unsigned)bu[7] << 16);
    *reinterpret_cast<uint4*>(&Et[((size_t)(b * M + m)) * N + n0 + n8]) = pk;
  }
}

// ---------------------------------------------------------------------------
// K2: tokens_raw[b,m,d] += sum_n Et[b,m,n] * xbT[b,d,n]   (split-K over N)
// grid (D/64, N/512, B), block 256
__global__ __launch_bounds__(256) void k2_pool(
    const unsigned short* __restrict__ Et, const unsigned short* __restrict__ xbT,
    float* __restrict__ tokens) {
  __shared__ unsigned short EtS[64][72];
  __shared__ unsigned short XtS[64][72];
  const int dt = blockIdx.x, nc = blockIdx.y, b = blockIdx.z;
  const int d0 = dt * 64;
  const int tid = threadIdx.x;
  const int w = tid >> 6, l = tid & 63;
  floatx4 acc[4] = {{0.f, 0.f, 0.f, 0.f},
                    {0.f, 0.f, 0.f, 0.f},
                    {0.f, 0.f, 0.f, 0.f},
                    {0.f, 0.f, 0.f, 0.f}};
  const int q8 = (l >> 4) * 8;
  for (int kc = 0; kc < 8; ++kc) {
    const int nb = nc * 512 + kc * 64;
    __syncthreads();
#pragma unroll
    for (int p = 0; p < 2; ++p) {
      const int g = p * 256 + tid;
      const int row = g >> 3;
      const int c8 = (g & 7) * 8;
      *reinterpret_cast<short8*>(&EtS[row][c8]) =
          *reinterpret_cast<const short8*>(
              &Et[((size_t)(b * M + row)) * N + nb + c8]);
      *reinterpret_cast<short8*>(&XtS[row][c8]) =
          *reinterpret_cast<const short8*>(
              &xbT[((size_t)(b * D + d0 + row)) * N + nb + c8]);
    }
    __syncthreads();
#pragma unroll
    for (int ks = 0; ks < 2; ++ks) {
      short8 a = *reinterpret_cast<short8*>(&EtS[w * 16 + (l & 15)][ks * 32 + q8]);
#pragma unroll
      for (int dtile = 0; dtile < 4; ++dtile) {
        short8 bf = *reinterpret_cast<short8*>(
            &XtS[dtile * 16 + (l & 15)][ks * 32 + q8]);
        acc[dtile] =
            __builtin_amdgcn_mfma_f32_16x16x32_bf16(a, bf, acc[dtile], 0, 0, 0);
      }
    }
  }
#pragma unroll
  for (int dtile = 0; dtile < 4; ++dtile)
#pragma unroll
    for (int r = 0; r < 4; ++r) {
      const int m = w * 16 + (l >> 4) * 4 + r;
      const int d = d0 + dtile * 16 + (l & 15);
      atomicAdd(&tokens[((size_t)(b * M + m)) * D + d], acc[dtile][r]);
    }
}

// ---------------------------------------------------------------------------
// K3/K5: Out[b,m,e] = (A[b,m,:] . W[e,:] + bias[e]) / denom[b,m]   (fp32)
// mode 0: write OutF fp32 [b,m,EC].  mode 1: write OutT bf16 [b,e,m] (EC=256).
// grid (EC/64, B), block 256
__global__ __launch_bounds__(256) void k_proj(
    const float* __restrict__ A, const float* __restrict__ W,
    const float* __restrict__ bias, const float* __restrict__ denom,
    float* __restrict__ OutF, unsigned short* __restrict__ OutT, const int EC,
    const int mode) {
  __shared__ float At[32][68];
  __shared__ float Bt[32][68];
  __shared__ float Cs[64][68];
  const int et = blockIdx.x;
  const int b = blockIdx.y;
  const int tid = threadIdx.x;
  const int tm4 = (tid & 15) * 4;  // e
  const int tn4 = (tid >> 4) * 4;  // m
  float acc[4][4] = {};
  for (int kc = 0; kc < 8; ++kc) {
    __syncthreads();
    for (int i = tid; i < 512; i += 256) {
      const int r = i >> 3;
      const int kq = (i & 7) * 4;
      float4 av = ld4(&A[((size_t)(b * M + r)) * D + kc * 32 + kq]);
      At[kq + 0][r] = av.x; At[kq + 1][r] = av.y;
      At[kq + 2][r] = av.z; At[kq + 3][r] = av.w;
      float4 wv = ld4(&W[((size_t)(et * 64 + r)) * D + kc * 32 + kq]);
      Bt[kq + 0][r] = wv.x; Bt[kq + 1][r] = wv.y;
      Bt[kq + 2][r] = wv.z; Bt[kq + 3][r] = wv.w;
    }
    __syncthreads();
    for (int k = 0; k < 32; ++k) {
      float4 a4 = ld4(&At[k][tn4]);
      float4 b4 = ld4(&Bt[k][tm4]);
      FMA16(acc, a4, b4);
    }
  }
  float bsv[4] = {0.f, 0.f, 0.f, 0.f};
  if (bias != nullptr) {
    float4 t = ld4(&bias[et * 64 + tm4]);
    bsv[0] = t.x; bsv[1] = t.y; bsv[2] = t.z; bsv[3] = t.w;
  }
  if (mode == 0) {
#pragma unroll
    for (int i = 0; i < 4; ++i) {
      const float rcp = 1.0f / denom[b * M + tn4 + i];
      st4(&OutF[((size_t)(b * M + tn4 + i)) * EC + et * 64 + tm4],
          (acc[i][0] + bsv[0]) * rcp, (acc[i][1] + bsv[1]) * rcp,
          (acc[i][2] + bsv[2]) * rcp, (acc[i][3] + bsv[3]) * rcp);
    }
  } else {
#pragma unroll
    for (int i = 0; i < 4; ++i) {
      const float rcp = 1.0f / denom[b * M + tn4 + i];
#pragma unroll
      for (int j = 0; j < 4; ++j)
        Cs[tn4 + i][tm4 + j] = (acc[i][j] + bsv[j]) * rcp;
    }
    __syncthreads();
    // transposed bf16 write: OutT[b, e, m]
#pragma unroll
    for (int p = 0; p < 2; ++p) {
      const int g = p * 256 + tid;
      const int e = g >> 3;       // 0..63
      const int m0 = (g & 7) * 8;
      unsigned short bu[8];
#pragma unroll
      for (int k = 0; k < 8; ++k) bu[k] = f2bf(Cs[m0 + k][e]);
      uint4 pk;
      pk.x = (unsigned)bu[0] | ((unsigned)bu[1] << 16);
      pk.y = (unsigned)bu[2] | ((unsigned)bu[3] << 16);
      pk.z = (unsigned)bu[4] | ((unsigned)bu[5] << 16);
      pk.w = (unsigned)bu[6] | ((unsigned)bu[7] << 16);
      *reinterpret_cast<uint4*>(
          &OutT[((size_t)(b * D + et * 64 + e)) * M + m0]) = pk;
    }
  }
}

// ---------------------------------------------------------------------------
// K4: per (b,h) attention over M=64 tokens, HD=32 (fp32, unchanged)
// grid (B*H), block 256
__global__ __launch_bounds__(256) void k4_attn(
    const float* __restrict__ qkv, float* __restrict__ attn_o) {
  __shared__ float qt[32][68];
  __shared__ float kt[32][68];
  __shared__ float vv[64][36];
  __shared__ float P[64][68];
  const int b = blockIdx.x >> 3;
  const int h = blockIdx.x & 7;
  const int tid = threadIdx.x;
  for (int i = tid; i < 512; i += 256) {
    const int m = i >> 3;
    const int c4 = (i & 7) * 4;
    const float* base = &qkv[((size_t)(b * M + m)) * 768 + h * 32 + c4];
    float4 q4 = ld4(base);
    float4 k4 = ld4(base + 256);
    float4 v4 = ld4(base + 512);
    qt[c4 + 0][m] = q4.x; qt[c4 + 1][m] = q4.y; qt[c4 + 2][m] = q4.z; qt[c4 + 3][m] = q4.w;
    kt[c4 + 0][m] = k4.x; kt[c4 + 1][m] = k4.y; kt[c4 + 2][m] = k4.z; kt[c4 + 3][m] = k4.w;
    *reinterpret_cast<float4*>(&vv[m][c4]) = v4;
  }
  __syncthreads();
  {
    const int tm4 = (tid & 15) * 4;
    const int tn4 = (tid >> 4) * 4;
    float acc[4][4] = {};
    for (int k = 0; k < 32; ++k) {
      float4 a4 = ld4(&qt[k][tn4]);
      float4 b4 = ld4(&kt[k][tm4]);
      FMA16(acc, a4, b4);
    }
    const float scale = 0.17677669529663687f;
#pragma unroll
    for (int i = 0; i < 4; ++i)
      st4(&P[tn4 + i][tm4], acc[i][0] * scale, acc[i][1] * scale,
          acc[i][2] * scale, acc[i][3] * scale);
  }
  __syncthreads();
  if (tid < 64) {
    float mx = -1e30f;
    for (int j = 0; j < 64; ++j) mx = fmaxf(mx, P[tid][j]);
    float s = 0.0f;
    for (int j = 0; j < 64; ++j) {
      const float e = expf(P[tid][j] - mx);
      P[tid][j] = e;
      s += e;
    }
    const float r = 1.0f / s;
    for (int j = 0; j < 64; ++j) P[tid][j] *= r;
  }
  __syncthreads();
  if (tid < 128) {
    const int i0 = (tid >> 3) * 4;
    const int c0 = (tid & 7) * 4;
    float o[4][4] = {};
    for (int j = 0; j < 64; ++j) {
      float4 v4 = ld4(&vv[j][c0]);
#pragma unroll
      for (int ii = 0; ii < 4; ++ii) {
        const float p = P[i0 + ii][j];
        o[ii][0] = fmaf(p, v4.x, o[ii][0]);
        o[ii][1] = fmaf(p, v4.y, o[ii][1]);
        o[ii][2] = fmaf(p, v4.z, o[ii][2]);
        o[ii][3] = fmaf(p, v4.w, o[ii][3]);
      }
    }
#pragma unroll
    for (int ii = 0; ii < 4; ++ii)
      st4(&attn_o[((size_t)(b * M + i0 + ii)) * D + h * 32 + c0],
          o[ii][0], o[ii][1], o[ii][2], o[ii][3]);
  }
}

// ---------------------------------------------------------------------------
// K6: out[b,n,d] = sum_m En[b,n,m] * TpT[b,d,m]   (MFMA, K=64)
// grid (D/64, N/64, B), block 256
__global__ __launch_bounds__(256) void k6_unpool(
    const unsigned short* __restrict__ En, const unsigned short* __restrict__ TpT,
    float* __restrict__ out) {
  __shared__ unsigned short EnS[64][72];
  __shared__ unsigned short TpS[64][72];
  const int dt = blockIdx.x, nt = blockIdx.y, b = blockIdx.z;
  const int n0 = nt * 64, d0 = dt * 64;
  const int tid = threadIdx.x;
  const int w = tid >> 6, l = tid & 63;
#pragma unroll
  for (int p = 0; p < 2; ++p) {
    const int g = p * 256 + tid;
    const int row = g >> 3;
    const int c8 = (g & 7) * 8;
    *reinterpret_cast<short8*>(&EnS[row][c8]) =
        *reinterpret_cast<const short8*>(
            &En[((size_t)(b * N + n0 + row)) * M + c8]);
    *reinterpret_cast<short8*>(&TpS[row][c8]) =
        *reinterpret_cast<const short8*>(
            &TpT[((size_t)(b * D + d0 + row)) * M + c8]);
  }
  __syncthreads();
  floatx4 acc[4] = {{0.f, 0.f, 0.f, 0.f},
                    {0.f, 0.f, 0.f, 0.f},
                    {0.f, 0.f, 0.f, 0.f},
                    {0.f, 0.f, 0.f, 0.f}};
  const int q8 = (l >> 4) * 8;
#pragma unroll
  for (int ks = 0; ks < 2; ++ks) {
    short8 a = *reinterpret_cast<short8*>(&EnS[w * 16 + (l & 15)][ks * 32 + q8]);
#pragma unroll
    for (int dtile = 0; dtile < 4; ++dtile) {
      short8 bf = *reinterpret_cast<short8*>(
          &TpS[dtile * 16 + (l & 15)][ks * 32 + q8]);
      acc[dtile] =
          __builtin_amdgcn_mfma_f32_16x16x32_bf16(a, bf, acc[dtile], 0, 0, 0);
    }
  }
#pragma unroll
  for (int dtile = 0; dtile < 4; ++dtile)
#pragma unroll
    for (int r = 0; r < 4; ++r) {
      const int n = n0 + w * 16 + (l >> 4) * 4 + r;
      const int d = d0 + dtile * 16 + (l & 15);
      out[((size_t)(b * N + n)) * D + d] = acc[dtile][r];
    }
}

// ---------------------------------------------------------------------------
extern "C" void kernel_launch(void* const* d_in, const int* in_sizes, int n_in,
                              void* d_out, int out_size, void* d_ws,
                              size_t ws_size, hipStream_t stream) {
  const float* x = (const float*)d_in[0];
  const float* Ws = (const float*)d_in[1];
  const float* bs = (const float*)d_in[2];
  const float* Wqkv = (const float*)d_in[3];
  const float* Wo = (const float*)d_in[4];
  const float* bo = (const float*)d_in[5];
  float* out = (float*)d_out;

  char* p = (char*)d_ws;
  unsigned short* xb = (unsigned short*)p;       p += (size_t)B * N * D * 2;   // 33.5 MB
  unsigned short* xbT = (unsigned short*)p;      p += (size_t)B * N * D * 2;   // 33.5 MB
  unsigned short* En = (unsigned short*)p;       p += (size_t)B * N * M * 2;   // 8.4 MB
  unsigned short* Et = (unsigned short*)p;       p += (size_t)B * N * M * 2;   // 8.4 MB
  unsigned short* Wsb = (unsigned short*)p;      p += (size_t)M * D * 2;       // 32 KB
  unsigned short* TpT = (unsigned short*)p;      p += (size_t)B * D * M * 2;   // 128 KB
  float* denom = (float*)p;                      p += (size_t)B * M * 4;
  float* tokens = (float*)p;                     p += (size_t)B * M * D * 4;
  float* qkv = (float*)p;                        p += (size_t)B * M * 3 * D * 4;
  float* attn_o = (float*)p;                     p += (size_t)B * M * D * 4;

  hipMemsetAsync(denom, 0, (size_t)B * M * sizeof(float), stream);
  hipMemsetAsync(tokens, 0, (size_t)B * M * D * sizeof(float), stream);

  k0_cvt<<<dim3(N / 64, D / 64, B), 256, 0, stream>>>(x, Ws, xb, xbT, Wsb);
  k1_logits<<<dim3(N / 64, B), 256, 0, stream>>>(xb, Wsb, bs, En, Et, denom);
  k2_pool<<<dim3(D / 64, N / 512, B), 256, 0, stream>>>(Et, xbT, tokens);
  k_proj<<<dim3(12, B), 256, 0, stream>>>(tokens, Wqkv, nullptr, denom, qkv,
                                          nullptr, 768, 0);
  k4_attn<<<dim3(B * H), 256, 0, stream>>>(qkv, attn_o);
  k_proj<<<dim3(4, B), 256, 0, stream>>>(attn_o, Wo, bo, denom, nullptr, TpT,
                                         256, 1);
  k6_unpool<<<dim3(D / 64, N / 64, B), 256, 0, stream>>>(En, TpT, out);
}

// Round 3
// 190.748 us; speedup vs baseline: 1.5696x; 1.2090x over previous
//
#include <hip/hip_runtime.h>
#include <math.h>

constexpr int B = 4;
constexpr int N = 16384;
constexpr int D = 256;
constexpr int M = 64;
constexpr int H = 8;
// HD = 32, 3D = 768

typedef __attribute__((ext_vector_type(8))) short short8;
typedef __attribute__((ext_vector_type(4))) float floatx4;

__device__ __forceinline__ float4 ld4(const float* p) {
  return *reinterpret_cast<const float4*>(p);
}
__device__ __forceinline__ void st4(float* p, float a, float b, float c, float d) {
  *reinterpret_cast<float4*>(p) = make_float4(a, b, c, d);
}
__device__ __forceinline__ unsigned short f2bf(float f) {
  unsigned u = __float_as_uint(f);
  unsigned r = (u + 0x7fffu + ((u >> 16) & 1u)) >> 16;  // RNE
  return (unsigned short)r;
}

#define FMA16(acc, a4, b4)                       \
  do {                                           \
    acc[0][0] = fmaf(a4.x, b4.x, acc[0][0]);     \
    acc[0][1] = fmaf(a4.x, b4.y, acc[0][1]);     \
    acc[0][2] = fmaf(a4.x, b4.z, acc[0][2]);     \
    acc[0][3] = fmaf(a4.x, b4.w, acc[0][3]);     \
    acc[1][0] = fmaf(a4.y, b4.x, acc[1][0]);     \
    acc[1][1] = fmaf(a4.y, b4.y, acc[1][1]);     \
    acc[1][2] = fmaf(a4.y, b4.z, acc[1][2]);     \
    acc[1][3] = fmaf(a4.y, b4.w, acc[1][3]);     \
    acc[2][0] = fmaf(a4.z, b4.x, acc[2][0]);     \
    acc[2][1] = fmaf(a4.z, b4.y, acc[2][1]);     \
    acc[2][2] = fmaf(a4.z, b4.z, acc[2][2]);     \
    acc[2][3] = fmaf(a4.z, b4.w, acc[2][3]);     \
    acc[3][0] = fmaf(a4.w, b4.x, acc[3][0]);     \
    acc[3][1] = fmaf(a4.w, b4.y, acc[3][1]);     \
    acc[3][2] = fmaf(a4.w, b4.z, acc[3][2]);     \
    acc[3][3] = fmaf(a4.w, b4.w, acc[3][3]);     \
  } while (0)

// ---------------------------------------------------------------------------
// K1 (fused): reads x fp32 directly. Per 64-n tile:
//   - stage x -> Xt bf16 [n][d], Ws -> Wt bf16 [m][d] (L2-resident)
//   - MFMA logits GEMM, exp epilogue -> Es
//   - emit xbT[b,d,n] bf16 (LDS column transpose of Xt)
//   - emit En[b,n,m], Et[b,m,n] bf16; denom[b,m] atomics
// grid (N/64, B), block 256 (4 waves)
__global__ __launch_bounds__(256) void k1_fused(
    const float* __restrict__ x, const float* __restrict__ Ws,
    const float* __restrict__ bs, unsigned short* __restrict__ xbT,
    unsigned short* __restrict__ En, unsigned short* __restrict__ Et,
    float* __restrict__ denom) {
  __shared__ unsigned short Xt[64][264];  // x tile [n][d] bf16
  __shared__ unsigned short Wt[64][264];  // Ws tile [m][d] bf16
  __shared__ unsigned short Es[64][72];   // E tile [n][m] bf16
  __shared__ float red[64];
  const int b = blockIdx.y;
  const int n0 = blockIdx.x * 64;
  const int tid = threadIdx.x;
  const int w = tid >> 6, l = tid & 63;

  // stage: 64x256 fp32 -> bf16, both x and Ws
#pragma unroll
  for (int p = 0; p < 16; ++p) {
    const int i = p * 256 + tid;
    const int row = i >> 6;          // 0..63
    const int c4 = (i & 63) * 4;     // 0..252
    float4 v = ld4(&x[((size_t)(b * N + n0 + row)) * D + c4]);
    unsigned u0 = (unsigned)f2bf(v.x) | ((unsigned)f2bf(v.y) << 16);
    unsigned u1 = (unsigned)f2bf(v.z) | ((unsigned)f2bf(v.w) << 16);
    *reinterpret_cast<uint2*>(&Xt[row][c4]) = make_uint2(u0, u1);
    float4 wv = ld4(&Ws[(size_t)row * D + c4]);
    unsigned w0 = (unsigned)f2bf(wv.x) | ((unsigned)f2bf(wv.y) << 16);
    unsigned w1 = (unsigned)f2bf(wv.z) | ((unsigned)f2bf(wv.w) << 16);
    *reinterpret_cast<uint2*>(&Wt[row][c4]) = make_uint2(w0, w1);
  }
  if (tid < 64) red[tid] = 0.0f;
  __syncthreads();

  // MFMA logits GEMM: C[n, m] = sum_d x[n,d] * Ws[m,d]
  floatx4 acc[4] = {{0.f, 0.f, 0.f, 0.f},
                    {0.f, 0.f, 0.f, 0.f},
                    {0.f, 0.f, 0.f, 0.f},
                    {0.f, 0.f, 0.f, 0.f}};
  const int ar = w * 16 + (l & 15);
  const int q8 = (l >> 4) * 8;
#pragma unroll
  for (int ks = 0; ks < 8; ++ks) {
    short8 a = *reinterpret_cast<short8*>(&Xt[ar][ks * 32 + q8]);
#pragma unroll
    for (int mt = 0; mt < 4; ++mt) {
      short8 bf = *reinterpret_cast<short8*>(&Wt[mt * 16 + (l & 15)][ks * 32 + q8]);
      acc[mt] = __builtin_amdgcn_mfma_f32_16x16x32_bf16(a, bf, acc[mt], 0, 0, 0);
    }
  }

  // xbT emit: thread tid owns d-row = tid; column-read Xt (lane-adjacent u16
  // reads share dwords -> <=2-way, free), pack, 16B stores to own 128B row.
  {
    const int t = tid;
#pragma unroll
    for (int g = 0; g < 4; ++g) {
      unsigned dw[8];
#pragma unroll
      for (int j = 0; j < 8; ++j) {
        const unsigned lo = Xt[g * 16 + 2 * j][t];
        const unsigned hi = Xt[g * 16 + 2 * j + 1][t];
        dw[j] = lo | (hi << 16);
      }
      const size_t base = ((size_t)(b * D + t)) * N + n0 + g * 16;
      *reinterpret_cast<uint4*>(&xbT[base]) =
          make_uint4(dw[0], dw[1], dw[2], dw[3]);
      *reinterpret_cast<uint4*>(&xbT[base + 8]) =
          make_uint4(dw[4], dw[5], dw[6], dw[7]);
    }
  }

  // epilogue: exp + Es + denom partials
#pragma unroll
  for (int mt = 0; mt < 4; ++mt) {
    const int m = mt * 16 + (l & 15);
    const float bsm = bs[m];
    float s = 0.0f;
#pragma unroll
    for (int r = 0; r < 4; ++r) {
      const int n = w * 16 + (l >> 4) * 4 + r;
      const float e = expf(acc[mt][r] + bsm);
      s += e;
      Es[n][m] = f2bf(e);
    }
    atomicAdd(&red[m], s);
  }
  __syncthreads();
  if (tid < 64) atomicAdd(&denom[b * M + tid], red[tid]);
  // En writes (row-major, coalesced b128)
#pragma unroll
  for (int p = 0; p < 2; ++p) {
    const int g = p * 256 + tid;
    const int n = g >> 3;
    const int m0 = (g & 7) * 8;
    short8 v = *reinterpret_cast<short8*>(&Es[n][m0]);
    *reinterpret_cast<short8*>(&En[((size_t)(b * N + n0 + n)) * M + m0]) = v;
  }
  // Et writes (transposed)
#pragma unroll
  for (int p = 0; p < 2; ++p) {
    const int g = p * 256 + tid;
    const int m = g >> 3;
    const int n8 = (g & 7) * 8;
    unsigned short bu[8];
#pragma unroll
    for (int k = 0; k < 8; ++k) bu[k] = Es[n8 + k][m];
    uint4 pk;
    pk.x = (unsigned)bu[0] | ((unsigned)bu[1] << 16);
    pk.y = (unsigned)bu[2] | ((unsigned)bu[3] << 16);
    pk.z = (unsigned)bu[4] | ((unsigned)bu[5] << 16);
    pk.w = (unsigned)bu[6] | ((unsigned)bu[7] << 16);
    *reinterpret_cast<uint4*>(&Et[((size_t)(b * M + m)) * N + n0 + n8]) = pk;
  }
}

// ---------------------------------------------------------------------------
// K2: tokens_raw[b,m,d] += sum_n Et[b,m,n] * xbT[b,d,n]   (split-K over N)
// grid (D/64, N/512, B), block 256
__global__ __launch_bounds__(256) void k2_pool(
    const unsigned short* __restrict__ Et, const unsigned short* __restrict__ xbT,
    float* __restrict__ tokens) {
  __shared__ unsigned short EtS[64][72];
  __shared__ unsigned short XtS[64][72];
  const int dt = blockIdx.x, nc = blockIdx.y, b = blockIdx.z;
  const int d0 = dt * 64;
  const int tid = threadIdx.x;
  const int w = tid >> 6, l = tid & 63;
  floatx4 acc[4] = {{0.f, 0.f, 0.f, 0.f},
                    {0.f, 0.f, 0.f, 0.f},
                    {0.f, 0.f, 0.f, 0.f},
                    {0.f, 0.f, 0.f, 0.f}};
  const int q8 = (l >> 4) * 8;
  for (int kc = 0; kc < 8; ++kc) {
    const int nb = nc * 512 + kc * 64;
    __syncthreads();
#pragma unroll
    for (int p = 0; p < 2; ++p) {
      const int g = p * 256 + tid;
      const int row = g >> 3;
      const int c8 = (g & 7) * 8;
      *reinterpret_cast<short8*>(&EtS[row][c8]) =
          *reinterpret_cast<const short8*>(
              &Et[((size_t)(b * M + row)) * N + nb + c8]);
      *reinterpret_cast<short8*>(&XtS[row][c8]) =
          *reinterpret_cast<const short8*>(
              &xbT[((size_t)(b * D + d0 + row)) * N + nb + c8]);
    }
    __syncthreads();
#pragma unroll
    for (int ks = 0; ks < 2; ++ks) {
      short8 a = *reinterpret_cast<short8*>(&EtS[w * 16 + (l & 15)][ks * 32 + q8]);
#pragma unroll
      for (int dtile = 0; dtile < 4; ++dtile) {
        short8 bf = *reinterpret_cast<short8*>(
            &XtS[dtile * 16 + (l & 15)][ks * 32 + q8]);
        acc[dtile] =
            __builtin_amdgcn_mfma_f32_16x16x32_bf16(a, bf, acc[dtile], 0, 0, 0);
      }
    }
  }
#pragma unroll
  for (int dtile = 0; dtile < 4; ++dtile)
#pragma unroll
    for (int r = 0; r < 4; ++r) {
      const int m = w * 16 + (l >> 4) * 4 + r;
      const int d = d0 + dtile * 16 + (l & 15);
      atomicAdd(&tokens[((size_t)(b * M + m)) * D + d], acc[dtile][r]);
    }
}

// ---------------------------------------------------------------------------
// K3/K5 (MFMA): Out[b,m,e] = (A[b,m,:] . W[e,:] + bias[e]) / denom[b,m]
// A, W fp32 in global; converted bf16 during staging. K = 256.
// mode 0: write OutF fp32 [b,m,EC].  mode 1: write OutT bf16 [b,e,m] (EC=256).
// grid (EC/64, B), block 256
__global__ __launch_bounds__(256) void k_proj(
    const float* __restrict__ A, const float* __restrict__ W,
    const float* __restrict__ bias, const float* __restrict__ denom,
    float* __restrict__ OutF, unsigned short* __restrict__ OutT, const int EC,
    const int mode) {
  __shared__ unsigned short At[64][264];
  __shared__ unsigned short Wt[64][264];
  __shared__ float Cs[64][68];
  const int et = blockIdx.x;
  const int b = blockIdx.y;
  const int tid = threadIdx.x;
  const int w = tid >> 6, l = tid & 63;
#pragma unroll
  for (int p = 0; p < 16; ++p) {
    const int i = p * 256 + tid;
    const int row = i >> 6;
    const int c4 = (i & 63) * 4;
    float4 av = ld4(&A[((size_t)(b * M + row)) * D + c4]);
    unsigned a0 = (unsigned)f2bf(av.x) | ((unsigned)f2bf(av.y) << 16);
    unsigned a1 = (unsigned)f2bf(av.z) | ((unsigned)f2bf(av.w) << 16);
    *reinterpret_cast<uint2*>(&At[row][c4]) = make_uint2(a0, a1);
    float4 wv = ld4(&W[((size_t)(et * 64 + row)) * D + c4]);
    unsigned w0 = (unsigned)f2bf(wv.x) | ((unsigned)f2bf(wv.y) << 16);
    unsigned w1 = (unsigned)f2bf(wv.z) | ((unsigned)f2bf(wv.w) << 16);
    *reinterpret_cast<uint2*>(&Wt[row][c4]) = make_uint2(w0, w1);
  }
  __syncthreads();
  floatx4 acc[4] = {{0.f, 0.f, 0.f, 0.f},
                    {0.f, 0.f, 0.f, 0.f},
                    {0.f, 0.f, 0.f, 0.f},
                    {0.f, 0.f, 0.f, 0.f}};
  const int ar = w * 16 + (l & 15);
  const int q8 = (l >> 4) * 8;
#pragma unroll
  for (int ks = 0; ks < 8; ++ks) {
    short8 a = *reinterpret_cast<short8*>(&At[ar][ks * 32 + q8]);
#pragma unroll
    for (int mt = 0; mt < 4; ++mt) {
      short8 bf = *reinterpret_cast<short8*>(&Wt[mt * 16 + (l & 15)][ks * 32 + q8]);
      acc[mt] = __builtin_amdgcn_mfma_f32_16x16x32_bf16(a, bf, acc[mt], 0, 0, 0);
    }
  }
  if (mode == 0) {
#pragma unroll
    for (int mt = 0; mt < 4; ++mt) {
#pragma unroll
      for (int r = 0; r < 4; ++r) {
        const int row = w * 16 + (l >> 4) * 4 + r;  // m
        const float rcp = 1.0f / denom[b * M + row];
        const int e = et * 64 + mt * 16 + (l & 15);
        OutF[((size_t)(b * M + row)) * EC + e] = acc[mt][r] * rcp;
      }
    }
  } else {
#pragma unroll
    for (int mt = 0; mt < 4; ++mt) {
#pragma unroll
      for (int r = 0; r < 4; ++r) {
        const int row = w * 16 + (l >> 4) * 4 + r;  // m
        const float rcp = 1.0f / denom[b * M + row];
        const int el = mt * 16 + (l & 15);
        const float bv = bias[et * 64 + el];
        Cs[row][el] = (acc[mt][r] + bv) * rcp;
      }
    }
    __syncthreads();
    // transposed bf16 write: OutT[b, e, m]
#pragma unroll
    for (int p = 0; p < 2; ++p) {
      const int g = p * 256 + tid;
      const int e = g >> 3;       // 0..63
      const int m0 = (g & 7) * 8;
      unsigned short bu[8];
#pragma unroll
      for (int k = 0; k < 8; ++k) bu[k] = f2bf(Cs[m0 + k][e]);
      uint4 pk;
      pk.x = (unsigned)bu[0] | ((unsigned)bu[1] << 16);
      pk.y = (unsigned)bu[2] | ((unsigned)bu[3] << 16);
      pk.z = (unsigned)bu[4] | ((unsigned)bu[5] << 16);
      pk.w = (unsigned)bu[6] | ((unsigned)bu[7] << 16);
      *reinterpret_cast<uint4*>(
          &OutT[((size_t)(b * D + et * 64 + e)) * M + m0]) = pk;
    }
  }
}

// ---------------------------------------------------------------------------
// K4: per (b,h) attention over M=64 tokens, HD=32 (fp32)
// grid (B*H), block 256
__global__ __launch_bounds__(256) void k4_attn(
    const float* __restrict__ qkv, float* __restrict__ attn_o) {
  __shared__ float qt[32][68];
  __shared__ float kt[32][68];
  __shared__ float vv[64][36];
  __shared__ float P[64][68];
  const int b = blockIdx.x >> 3;
  const int h = blockIdx.x & 7;
  const int tid = threadIdx.x;
  for (int i = tid; i < 512; i += 256) {
    const int m = i >> 3;
    const int c4 = (i & 7) * 4;
    const float* base = &qkv[((size_t)(b * M + m)) * 768 + h * 32 + c4];
    float4 q4 = ld4(base);
    float4 k4 = ld4(base + 256);
    float4 v4 = ld4(base + 512);
    qt[c4 + 0][m] = q4.x; qt[c4 + 1][m] = q4.y; qt[c4 + 2][m] = q4.z; qt[c4 + 3][m] = q4.w;
    kt[c4 + 0][m] = k4.x; kt[c4 + 1][m] = k4.y; kt[c4 + 2][m] = k4.z; kt[c4 + 3][m] = k4.w;
    *reinterpret_cast<float4*>(&vv[m][c4]) = v4;
  }
  __syncthreads();
  {
    const int tm4 = (tid & 15) * 4;
    const int tn4 = (tid >> 4) * 4;
    float acc[4][4] = {};
    for (int k = 0; k < 32; ++k) {
      float4 a4 = ld4(&qt[k][tn4]);
      float4 b4 = ld4(&kt[k][tm4]);
      FMA16(acc, a4, b4);
    }
    const float scale = 0.17677669529663687f;
#pragma unroll
    for (int i = 0; i < 4; ++i)
      st4(&P[tn4 + i][tm4], acc[i][0] * scale, acc[i][1] * scale,
          acc[i][2] * scale, acc[i][3] * scale);
  }
  __syncthreads();
  if (tid < 64) {
    float mx = -1e30f;
    for (int j = 0; j < 64; ++j) mx = fmaxf(mx, P[tid][j]);
    float s = 0.0f;
    for (int j = 0; j < 64; ++j) {
      const float e = expf(P[tid][j] - mx);
      P[tid][j] = e;
      s += e;
    }
    const float r = 1.0f / s;
    for (int j = 0; j < 64; ++j) P[tid][j] *= r;
  }
  __syncthreads();
  if (tid < 128) {
    const int i0 = (tid >> 3) * 4;
    const int c0 = (tid & 7) * 4;
    float o[4][4] = {};
    for (int j = 0; j < 64; ++j) {
      float4 v4 = ld4(&vv[j][c0]);
#pragma unroll
      for (int ii = 0; ii < 4; ++ii) {
        const float p = P[i0 + ii][j];
        o[ii][0] = fmaf(p, v4.x, o[ii][0]);
        o[ii][1] = fmaf(p, v4.y, o[ii][1]);
        o[ii][2] = fmaf(p, v4.z, o[ii][2]);
        o[ii][3] = fmaf(p, v4.w, o[ii][3]);
      }
    }
#pragma unroll
    for (int ii = 0; ii < 4; ++ii)
      st4(&attn_o[((size_t)(b * M + i0 + ii)) * D + h * 32 + c0],
          o[ii][0], o[ii][1], o[ii][2], o[ii][3]);
  }
}

// ---------------------------------------------------------------------------
// K6: out[b,n,d] = sum_m En[b,n,m] * TpT[b,d,m]   (MFMA, K=64)
// grid (D/64, N/64, B), block 256
__global__ __launch_bounds__(256) void k6_unpool(
    const unsigned short* __restrict__ En, const unsigned short* __restrict__ TpT,
    float* __restrict__ out) {
  __shared__ unsigned short EnS[64][72];
  __shared__ unsigned short TpS[64][72];
  const int dt = blockIdx.x, nt = blockIdx.y, b = blockIdx.z;
  const int n0 = nt * 64, d0 = dt * 64;
  const int tid = threadIdx.x;
  const int w = tid >> 6, l = tid & 63;
#pragma unroll
  for (int p = 0; p < 2; ++p) {
    const int g = p * 256 + tid;
    const int row = g >> 3;
    const int c8 = (g & 7) * 8;
    *reinterpret_cast<short8*>(&EnS[row][c8]) =
        *reinterpret_cast<const short8*>(
            &En[((size_t)(b * N + n0 + row)) * M + c8]);
    *reinterpret_cast<short8*>(&TpS[row][c8]) =
        *reinterpret_cast<const short8*>(
            &TpT[((size_t)(b * D + d0 + row)) * M + c8]);
  }
  __syncthreads();
  floatx4 acc[4] = {{0.f, 0.f, 0.f, 0.f},
                    {0.f, 0.f, 0.f, 0.f},
                    {0.f, 0.f, 0.f, 0.f},
                    {0.f, 0.f, 0.f, 0.f}};
  const int q8 = (l >> 4) * 8;
#pragma unroll
  for (int ks = 0; ks < 2; ++ks) {
    short8 a = *reinterpret_cast<short8*>(&EnS[w * 16 + (l & 15)][ks * 32 + q8]);
#pragma unroll
    for (int dtile = 0; dtile < 4; ++dtile) {
      short8 bf = *reinterpret_cast<short8*>(
          &TpS[dtile * 16 + (l & 15)][ks * 32 + q8]);
      acc[dtile] =
          __builtin_amdgcn_mfma_f32_16x16x32_bf16(a, bf, acc[dtile], 0, 0, 0);
    }
  }
#pragma unroll
  for (int dtile = 0; dtile < 4; ++dtile)
#pragma unroll
    for (int r = 0; r < 4; ++r) {
      const int n = n0 + w * 16 + (l >> 4) * 4 + r;
      const int d = d0 + dtile * 16 + (l & 15);
      out[((size_t)(b * N + n)) * D + d] = acc[dtile][r];
    }
}

// ---------------------------------------------------------------------------
extern "C" void kernel_launch(void* const* d_in, const int* in_sizes, int n_in,
                              void* d_out, int out_size, void* d_ws,
                              size_t ws_size, hipStream_t stream) {
  const float* x = (const float*)d_in[0];
  const float* Ws = (const float*)d_in[1];
  const float* bs = (const float*)d_in[2];
  const float* Wqkv = (const float*)d_in[3];
  const float* Wo = (const float*)d_in[4];
  const float* bo = (const float*)d_in[5];
  float* out = (float*)d_out;

  char* p = (char*)d_ws;
  unsigned short* xbT = (unsigned short*)p;      p += (size_t)B * N * D * 2;   // 33.5 MB
  unsigned short* En = (unsigned short*)p;       p += (size_t)B * N * M * 2;   // 8.4 MB
  unsigned short* Et = (unsigned short*)p;       p += (size_t)B * N * M * 2;   // 8.4 MB
  unsigned short* TpT = (unsigned short*)p;      p += (size_t)B * D * M * 2;   // 128 KB
  float* denom = (float*)p;                      p += (size_t)B * M * 4;
  float* tokens = (float*)p;                     p += (size_t)B * M * D * 4;
  float* qkv = (float*)p;                        p += (size_t)B * M * 3 * D * 4;
  float* attn_o = (float*)p;                     p += (size_t)B * M * D * 4;

  hipMemsetAsync(denom, 0, (size_t)B * M * sizeof(float), stream);
  hipMemsetAsync(tokens, 0, (size_t)B * M * D * sizeof(float), stream);

  k1_fused<<<dim3(N / 64, B), 256, 0, stream>>>(x, Ws, bs, xbT, En, Et, denom);
  k2_pool<<<dim3(D / 64, N / 512, B), 256, 0, stream>>>(Et, xbT, tokens);
  k_proj<<<dim3(12, B), 256, 0, stream>>>(tokens, Wqkv, nullptr, denom, qkv,
                                          nullptr, 768, 0);
  k4_attn<<<dim3(B * H), 256, 0, stream>>>(qkv, attn_o);
  k_proj<<<dim3(4, B), 256, 0, stream>>>(attn_o, Wo, bo, denom, nullptr, TpT,
                                         256, 1);
  k6_unpool<<<dim3(D / 64, N / 64, B), 256, 0, stream>>>(En, TpT, out);
}